// Round 7
// baseline (436.119 us; speedup 1.0000x reference)
//
#include <hip/hip_runtime.h>

typedef float v2f __attribute__((ext_vector_type(2)));
typedef float v4f __attribute__((ext_vector_type(4)));

#define N_ROWS 131072
#define DIM    256
#define KP     16
#define NDOM   8
#define NB     32      // bins
#define GG     100     // barycenter grid

#define EB_N   (NDOM*KP*(NB+1))   // 4224 floats
#define BARY_N (KP*GG)            // 1600

#define GRID   1536
#define WAVES  4
#define NWAVE  (GRID*WAVES)       // 6144 waves
#define ITERS  22                 // 21 or 22 rows per wave (tail-guarded)

__device__ __forceinline__ void pk_fma(v2f &d, v2f a, v2f b) {
    asm("v_pk_fma_f32 %0, %1, %2, %0" : "+v"(d) : "v"(a), "v"(b));
}
// gfx950 half-swap ops: after swap, a+b = per-half partial sums (no cndmask select)
__device__ __forceinline__ void pl32swap(float &a, float &b) {
    asm("v_permlane32_swap_b32 %0, %1" : "+v"(a), "+v"(b));
}
__device__ __forceinline__ void pl16swap(float &a, float &b) {
    asm("v_permlane16_swap_b32 %0, %1" : "+v"(a), "+v"(b));
}
// swap vector elements via scalar locals (asm can't bind vector elements)
__device__ __forceinline__ v2f swap32_sum(v2f lo, v2f hi) {
    float a0 = lo[0], b0 = hi[0], a1 = lo[1], b1 = hi[1];
    pl32swap(a0, b0); pl32swap(a1, b1);
    v2f r; r[0] = a0 + b0; r[1] = a1 + b1; return r;
}
__device__ __forceinline__ v2f swap16_sum(v2f lo, v2f hi) {
    float a0 = lo[0], b0 = hi[0], a1 = lo[1], b1 = hi[1];
    pl16swap(a0, b0); pl16swap(a1, b1);
    v2f r; r[0] = a0 + b0; r[1] = a1 + b1; return r;
}
// ds_swizzle pattern must be an integer-constant-expression -> template param
template <int CODE>
__device__ __forceinline__ float swzf(float x) {
    return __builtin_bit_cast(float,
        __builtin_amdgcn_ds_swizzle(__builtin_bit_cast(int, x), CODE));
}
template <int M>
__device__ __forceinline__ void xor_sum2(v2f &a, v2f &b) {
    constexpr int CODE = (M << 10) | 0x1F;   // BitMode xor_mask=M
    a[0] += swzf<CODE>(a[0]); a[1] += swzf<CODE>(a[1]);
    b[0] += swzf<CODE>(b[0]); b[1] += swzf<CODE>(b[1]);
}
__device__ __forceinline__ void wave_fence() {
    asm volatile("s_waitcnt lgkmcnt(0)" ::: "memory");
    __builtin_amdgcn_sched_barrier(0);  // rule #18
}

__global__ __launch_bounds__(256, 6)
void inb_kernel(const float* __restrict__ X, const int* __restrict__ y,
                const float* __restrict__ wT, const float* __restrict__ be,
                const float* __restrict__ cv, const float* __restrict__ bq,
                float* __restrict__ out)
{
    // LDS: 16896 + 6400 + 256 = 23552 B -> 6 blocks/CU (sCDF moved to L1/L2)
    __shared__ float sEB[EB_N];
    __shared__ float sBARY[BARY_N];
    __shared__ float sCOEFF[WAVES][16];

    const int tid = threadIdx.x;
    for (int i = tid; i < EB_N; i += 256) sEB[i] = be[i];
    for (int i = tid; i < BARY_N; i += 256) sBARY[i] = bq[i];
    __syncthreads();

    const int lane = tid & 63;
    const int wid  = tid >> 6;
    // k lives in lane bits 0,1,4,5; redundancy (edge-chunk) in bits 2,3
    const int k      = ((lane & 48) >> 2) | (lane & 3);
    const int echunk = (lane >> 2) & 3;

    // wT rows 4l..4l+3, all 16 k — serves projection partials AND output GEMM
    v2f wTo[4][8];
#pragma unroll
    for (int j = 0; j < 4; ++j) {
        const v4f* wrow = reinterpret_cast<const v4f*>(&wT[(4*lane + j)*KP]);
#pragma unroll
        for (int q = 0; q < 4; ++q) {
            v4f v = wrow[q];
            v2f a; a[0] = v[0]; a[1] = v[1]; wTo[j][2*q]   = a;
            v2f b; b[0] = v[2]; b[1] = v[3]; wTo[j][2*q+1] = b;
        }
    }

    float* cobuf = sCOEFF[wid];
    const int gwave = blockIdx.x * WAVES + wid;

    // prefetch distance 2 on X, distance 1 on y
    v4f x_cur = *reinterpret_cast<const v4f*>(&X[(size_t)gwave*DIM + 4*lane]);
    int pr1 = (gwave + NWAVE < N_ROWS) ? gwave + NWAVE : gwave;
    v4f x_nxt = *reinterpret_cast<const v4f*>(&X[(size_t)pr1*DIM + 4*lane]);
    int dom_cur = y[gwave];

    for (int it = 0; it < ITERS; ++it) {
        const int row = gwave + it*NWAVE;
        if (row >= N_ROWS) break;

        // ---- edge reads: depend only on prefetched dom -> issue first ----
        const float* ebRow = &sEB[(dom_cur*KP + k)*(NB+1)];
        float e[8];
#pragma unroll
        for (int t = 0; t < 8; ++t) e[t] = ebRow[8*echunk + t];

        // prefetches (clamped, branchless)
        int nr  = row + NWAVE;   if (nr  >= N_ROWS) nr  = row;
        int pfr = row + 2*NWAVE; if (pfr >= N_ROWS) pfr = row;
        int dom_nxt = y[nr];
        v4f x_pf = *reinterpret_cast<const v4f*>(&X[(size_t)pfr*DIM + 4*lane]);

        // ---- projection partials: P[q] = sum_j x[j]*wT[4l+j][2q..2q+1] ----
        v2f P[8];
#pragma unroll
        for (int q = 0; q < 8; ++q) { P[q][0] = 0.f; P[q][1] = 0.f; }
#pragma unroll
        for (int j = 0; j < 4; ++j) {
            v2f xj; xj[0] = x_cur[j]; xj[1] = x_cur[j];
#pragma unroll
            for (int q = 0; q < 8; ++q) pk_fma(P[q], xj, wTo[j][q]);
        }

        // ---- reduce-scatter: A(xor32) via permlane32_swap, B(xor16) via
        //      permlane16_swap, C-F(xor8..1) via ds_swizzle. No cndmask. ----
        v2f Q[4];
#pragma unroll
        for (int r = 0; r < 4; ++r)
            Q[r] = swap32_sum(P[r], P[r+4]);  // lanes<32: k=2r,2r+1 ; lanes>=32: +8
        v2f S0 = swap16_sum(Q[0], Q[2]);      // rows 0,2: koff 0,1 ; rows 1,3: koff 4,5
        v2f S1 = swap16_sum(Q[1], Q[3]);      // rows 0,2: koff 2,3 ; rows 1,3: koff 6,7
        xor_sum2<8>(S0, S1);
        xor_sum2<4>(S0, S1);
        xor_sum2<2>(S0, S1);
        xor_sum2<1>(S0, S1);
        // lane's k = 8*b5 + 4*b4 + (l&3): select S_{bit1}, component bit0
        v2f T = (lane & 2) ? S1 : S0;
        const float xm = (lane & 1) ? T[1] : T[0];

        // ---- count-based searchsorted over edges 0..31 (8 per redundant lane) ----
        int cnt = (e[0] <= xm) + (e[1] <= xm) + (e[2] <= xm) + (e[3] <= xm)
                + (e[4] <= xm) + (e[5] <= xm) + (e[6] <= xm) + (e[7] <= xm);
        cnt += __builtin_amdgcn_ds_swizzle(cnt, 0x101F);   // xor 4
        cnt += __builtin_amdgcn_ds_swizzle(cnt, 0x201F);   // xor 8
        int i0 = min(max(cnt - 1, 0), NB - 1);

        // dependent lookups: edges from LDS, cdf from L1/L2 (16.9 KB table)
        float x0 = ebRow[i0], x1 = ebRow[i0+1];
        const float* cfRow = cv + (size_t)(dom_cur*KP + k)*(NB+1);
        float f0 = cfRow[i0], f1 = cfRow[i0+1];

        float t  = fminf(fmaxf(__fdividef(xm - x0, x1 - x0), 0.f), 1.f);
        float u  = f0 + t * (f1 - f0);
        float posv = fminf(fmaxf(u, 0.f), 1.f) * (float)(GG - 1);
        int jj = min((int)posv, GG - 2);
        float ttf = posv - (float)jj;
        float b0 = sBARY[k*GG + jj], b1 = sBARY[k*GG + jj + 1];
        float z = b0*(1.f - ttf) + b1*ttf;
        float coeff = xm - z;                 // out = X - coeff @ wT.T

        if ((lane & 12) == 0) cobuf[k] = coeff;   // ec==0 lanes cover k=0..15
        wave_fence();

        // ---- output: out[4l+j] = x[j] - sum_k coeff[k]*wT[4l+j][k] ----
        v2f c2[8];
#pragma unroll
        for (int q = 0; q < 4; ++q) {
            v4f cv4 = *reinterpret_cast<const v4f*>(&cobuf[4*q]);   // broadcast
            v2f a; a[0] = cv4[0]; a[1] = cv4[1]; c2[2*q]   = a;
            v2f b; b[0] = cv4[2]; b[1] = cv4[3]; c2[2*q+1] = b;
        }
        float od[4];
#pragma unroll
        for (int j = 0; j < 4; ++j) {
            v2f a = {0.f,0.f};
#pragma unroll
            for (int q = 0; q < 8; ++q) pk_fma(a, c2[q], wTo[j][q]);
            od[j] = x_cur[j] - (a[0] + a[1]);
        }
        v4f o4; o4[0] = od[0]; o4[1] = od[1]; o4[2] = od[2]; o4[3] = od[3];
        *reinterpret_cast<v4f*>(&out[(size_t)row*DIM + 4*lane]) = o4;

        x_cur = x_nxt; x_nxt = x_pf; dom_cur = dom_nxt;
    }
}

extern "C" void kernel_launch(void* const* d_in, const int* in_sizes, int n_in,
                              void* d_out, int out_size, void* d_ws, size_t ws_size,
                              hipStream_t stream) {
    const float* X  = (const float*)d_in[0];
    const int*   y  = (const int*)  d_in[1];
    const float* wT = (const float*)d_in[2];
    const float* be = (const float*)d_in[3];
    const float* cv = (const float*)d_in[4];
    const float* bq = (const float*)d_in[5];
    float* out = (float*)d_out;
    hipLaunchKernelGGL(inb_kernel, dim3(GRID), dim3(256), 0, stream,
                       X, y, wT, be, cv, bq, out);
}

// Round 8
// 81.525 us; speedup vs baseline: 5.3495x; 5.3495x over previous
//
#include <hip/hip_runtime.h>

typedef float v2f __attribute__((ext_vector_type(2)));
typedef float v4f __attribute__((ext_vector_type(4)));

#define N_ROWS 131072
#define DIM    256
#define KP     16
#define NDOM   8
#define NB     32      // bins
#define GG     100     // barycenter grid

#define EB_N   (NDOM*KP*(NB+1))   // 4224 floats
#define BARY_N (KP*GG)            // 1600

#define GRID   1536
#define WAVES  4
#define NWAVE  (GRID*WAVES)       // 6144 waves
#define ITERS  22                 // 21 or 22 rows per wave (tail-guarded)

__device__ __forceinline__ void pk_fma(v2f &d, v2f a, v2f b) {
    asm("v_pk_fma_f32 %0, %1, %2, %0" : "+v"(d) : "v"(a), "v"(b));
}
// gfx950 half-swap ops: after swap, a+b = per-half partial sums (no cndmask select)
__device__ __forceinline__ void pl32swap(float &a, float &b) {
    asm("v_permlane32_swap_b32 %0, %1" : "+v"(a), "+v"(b));
}
__device__ __forceinline__ void pl16swap(float &a, float &b) {
    asm("v_permlane16_swap_b32 %0, %1" : "+v"(a), "+v"(b));
}
// swap vector elements via scalar locals (asm can't bind vector elements)
__device__ __forceinline__ v2f swap32_sum(v2f lo, v2f hi) {
    float a0 = lo[0], b0 = hi[0], a1 = lo[1], b1 = hi[1];
    pl32swap(a0, b0); pl32swap(a1, b1);
    v2f r; r[0] = a0 + b0; r[1] = a1 + b1; return r;
}
__device__ __forceinline__ v2f swap16_sum(v2f lo, v2f hi) {
    float a0 = lo[0], b0 = hi[0], a1 = lo[1], b1 = hi[1];
    pl16swap(a0, b0); pl16swap(a1, b1);
    v2f r; r[0] = a0 + b0; r[1] = a1 + b1; return r;
}
// ds_swizzle pattern must be an integer-constant-expression -> template param
template <int CODE>
__device__ __forceinline__ float swzf(float x) {
    return __builtin_bit_cast(float,
        __builtin_amdgcn_ds_swizzle(__builtin_bit_cast(int, x), CODE));
}
template <int M>
__device__ __forceinline__ void xor_sum2(v2f &a, v2f &b) {
    constexpr int CODE = (M << 10) | 0x1F;   // BitMode xor_mask=M
    a[0] += swzf<CODE>(a[0]); a[1] += swzf<CODE>(a[1]);
    b[0] += swzf<CODE>(b[0]); b[1] += swzf<CODE>(b[1]);
}
__device__ __forceinline__ void wave_fence() {
    asm volatile("s_waitcnt lgkmcnt(0)" ::: "memory");
    __builtin_amdgcn_sched_barrier(0);  // rule #18
}

__global__ __launch_bounds__(256, 4)   // 4 waves/EU: the proven-safe VGPR budget (R4)
void inb_kernel(const float* __restrict__ X, const int* __restrict__ y,
                const float* __restrict__ wT, const float* __restrict__ be,
                const float* __restrict__ cv, const float* __restrict__ bq,
                float* __restrict__ out)
{
    // LDS: 16896 + 6400 + 256 = 23552 B -> 6 blocks/CU (LDS-capped at 24 waves/CU)
    __shared__ float sEB[EB_N];
    __shared__ float sBARY[BARY_N];
    __shared__ float sCOEFF[WAVES][16];

    const int tid = threadIdx.x;
    for (int i = tid; i < EB_N; i += 256) sEB[i] = be[i];
    for (int i = tid; i < BARY_N; i += 256) sBARY[i] = bq[i];
    __syncthreads();

    const int lane = tid & 63;
    const int wid  = tid >> 6;
    // k lives in lane bits 0,1,4,5; redundancy (edge-chunk) in bits 2,3
    const int k      = ((lane & 48) >> 2) | (lane & 3);
    const int echunk = (lane >> 2) & 3;

    // wT rows 4l..4l+3, all 16 k — serves projection partials AND output GEMM
    v2f wTo[4][8];
#pragma unroll
    for (int j = 0; j < 4; ++j) {
        const v4f* wrow = reinterpret_cast<const v4f*>(&wT[(4*lane + j)*KP]);
#pragma unroll
        for (int q = 0; q < 4; ++q) {
            v4f v = wrow[q];
            v2f a; a[0] = v[0]; a[1] = v[1]; wTo[j][2*q]   = a;
            v2f b; b[0] = v[2]; b[1] = v[3]; wTo[j][2*q+1] = b;
        }
    }

    float* cobuf = sCOEFF[wid];
    const int gwave = blockIdx.x * WAVES + wid;

    // prefetch distance 2 on X, distance 1 on y
    v4f x_cur = *reinterpret_cast<const v4f*>(&X[(size_t)gwave*DIM + 4*lane]);
    int pr1 = (gwave + NWAVE < N_ROWS) ? gwave + NWAVE : gwave;
    v4f x_nxt = *reinterpret_cast<const v4f*>(&X[(size_t)pr1*DIM + 4*lane]);
    int dom_cur = y[gwave];

    for (int it = 0; it < ITERS; ++it) {
        const int row = gwave + it*NWAVE;
        if (row >= N_ROWS) break;

        // ---- edge reads: depend only on prefetched dom -> issue first ----
        const float* ebRow = &sEB[(dom_cur*KP + k)*(NB+1)];
        float e[8];
#pragma unroll
        for (int t = 0; t < 8; ++t) e[t] = ebRow[8*echunk + t];

        // prefetches (clamped, branchless)
        int nr  = row + NWAVE;   if (nr  >= N_ROWS) nr  = row;
        int pfr = row + 2*NWAVE; if (pfr >= N_ROWS) pfr = row;
        int dom_nxt = y[nr];
        v4f x_pf = *reinterpret_cast<const v4f*>(&X[(size_t)pfr*DIM + 4*lane]);

        // ---- projection partials: P[q] = sum_j x[j]*wT[4l+j][2q..2q+1] ----
        v2f P[8];
#pragma unroll
        for (int q = 0; q < 8; ++q) { P[q][0] = 0.f; P[q][1] = 0.f; }
#pragma unroll
        for (int j = 0; j < 4; ++j) {
            v2f xj; xj[0] = x_cur[j]; xj[1] = x_cur[j];
#pragma unroll
            for (int q = 0; q < 8; ++q) pk_fma(P[q], xj, wTo[j][q]);
        }

        // ---- reduce-scatter: A(xor32) via permlane32_swap, B(xor16) via
        //      permlane16_swap, C-F(xor8..1) via ds_swizzle. No cndmask. ----
        v2f Q[4];
#pragma unroll
        for (int r = 0; r < 4; ++r)
            Q[r] = swap32_sum(P[r], P[r+4]);  // lanes<32: k=2r,2r+1 ; lanes>=32: +8
        v2f S0 = swap16_sum(Q[0], Q[2]);      // rows 0,2: koff 0,1 ; rows 1,3: koff 4,5
        v2f S1 = swap16_sum(Q[1], Q[3]);      // rows 0,2: koff 2,3 ; rows 1,3: koff 6,7
        xor_sum2<8>(S0, S1);
        xor_sum2<4>(S0, S1);
        xor_sum2<2>(S0, S1);
        xor_sum2<1>(S0, S1);
        // lane's k = 8*b5 + 4*b4 + (l&3): select S_{bit1}, component bit0
        v2f T = (lane & 2) ? S1 : S0;
        const float xm = (lane & 1) ? T[1] : T[0];

        // ---- count-based searchsorted over edges 0..31 (8 per redundant lane) ----
        int cnt = (e[0] <= xm) + (e[1] <= xm) + (e[2] <= xm) + (e[3] <= xm)
                + (e[4] <= xm) + (e[5] <= xm) + (e[6] <= xm) + (e[7] <= xm);
        cnt += __builtin_amdgcn_ds_swizzle(cnt, 0x101F);   // xor 4
        cnt += __builtin_amdgcn_ds_swizzle(cnt, 0x201F);   // xor 8
        int i0 = min(max(cnt - 1, 0), NB - 1);

        // dependent lookups: edges from LDS, cdf from L1/L2 (16.9 KB table)
        float x0 = ebRow[i0], x1 = ebRow[i0+1];
        const float* cfRow = cv + (size_t)(dom_cur*KP + k)*(NB+1);
        float f0 = cfRow[i0], f1 = cfRow[i0+1];

        float t  = fminf(fmaxf(__fdividef(xm - x0, x1 - x0), 0.f), 1.f);
        float u  = f0 + t * (f1 - f0);
        float posv = fminf(fmaxf(u, 0.f), 1.f) * (float)(GG - 1);
        int jj = min((int)posv, GG - 2);
        float ttf = posv - (float)jj;
        float b0 = sBARY[k*GG + jj], b1 = sBARY[k*GG + jj + 1];
        float z = b0*(1.f - ttf) + b1*ttf;
        float coeff = xm - z;                 // out = X - coeff @ wT.T

        if ((lane & 12) == 0) cobuf[k] = coeff;   // ec==0 lanes cover k=0..15
        wave_fence();

        // ---- output: out[4l+j] = x[j] - sum_k coeff[k]*wT[4l+j][k] ----
        v2f c2[8];
#pragma unroll
        for (int q = 0; q < 4; ++q) {
            v4f cv4 = *reinterpret_cast<const v4f*>(&cobuf[4*q]);   // broadcast
            v2f a; a[0] = cv4[0]; a[1] = cv4[1]; c2[2*q]   = a;
            v2f b; b[0] = cv4[2]; b[1] = cv4[3]; c2[2*q+1] = b;
        }
        float od[4];
#pragma unroll
        for (int j = 0; j < 4; ++j) {
            v2f a = {0.f,0.f};
#pragma unroll
            for (int q = 0; q < 8; ++q) pk_fma(a, c2[q], wTo[j][q]);
            od[j] = x_cur[j] - (a[0] + a[1]);
        }
        v4f o4; o4[0] = od[0]; o4[1] = od[1]; o4[2] = od[2]; o4[3] = od[3];
        *reinterpret_cast<v4f*>(&out[(size_t)row*DIM + 4*lane]) = o4;

        x_cur = x_nxt; x_nxt = x_pf; dom_cur = dom_nxt;
    }
}

extern "C" void kernel_launch(void* const* d_in, const int* in_sizes, int n_in,
                              void* d_out, int out_size, void* d_ws, size_t ws_size,
                              hipStream_t stream) {
    const float* X  = (const float*)d_in[0];
    const int*   y  = (const int*)  d_in[1];
    const float* wT = (const float*)d_in[2];
    const float* be = (const float*)d_in[3];
    const float* cv = (const float*)d_in[4];
    const float* bq = (const float*)d_in[5];
    float* out = (float*)d_out;
    hipLaunchKernelGGL(inb_kernel, dim3(GRID), dim3(256), 0, stream,
                       X, y, wT, be, cv, bq, out);
}

// Round 9
// 71.103 us; speedup vs baseline: 6.1336x; 1.1466x over previous
//
#include <hip/hip_runtime.h>

typedef float v2f __attribute__((ext_vector_type(2)));
typedef float v4f __attribute__((ext_vector_type(4)));

#define N_ROWS 131072
#define DIM    256
#define KP     16
#define NDOM   8
#define NB     32      // bins
#define GG     100     // barycenter grid

#define EB_N   (NDOM*KP*(NB+1))   // 4224 floats
#define BARY_N (KP*GG)            // 1600

#define GRID   1024
#define WAVES  4
#define NWAVE  (GRID*WAVES)       // 4096 waves
#define PAIRS  16                 // 32 rows/wave, 2 rows per iteration, exact

__device__ __forceinline__ void pk_fma(v2f &d, v2f a, v2f b) {
    asm("v_pk_fma_f32 %0, %1, %2, %0" : "+v"(d) : "v"(a), "v"(b));
}
// gfx950 half-swap ops (VALU): after swap, a+b = per-half partial sums
__device__ __forceinline__ void pl32swap(float &a, float &b) {
    asm("v_permlane32_swap_b32 %0, %1" : "+v"(a), "+v"(b));
}
__device__ __forceinline__ void pl16swap(float &a, float &b) {
    asm("v_permlane16_swap_b32 %0, %1" : "+v"(a), "+v"(b));
}
__device__ __forceinline__ v2f swap32_sum(v2f lo, v2f hi) {
    float a0 = lo[0], b0 = hi[0], a1 = lo[1], b1 = hi[1];
    pl32swap(a0, b0); pl32swap(a1, b1);
    v2f r; r[0] = a0 + b0; r[1] = a1 + b1; return r;
}
__device__ __forceinline__ v2f swap16_sum(v2f lo, v2f hi) {
    float a0 = lo[0], b0 = hi[0], a1 = lo[1], b1 = hi[1];
    pl16swap(a0, b0); pl16swap(a1, b1);
    v2f r; r[0] = a0 + b0; r[1] = a1 + b1; return r;
}
// DPP cross-lane (VALU pipe, ~4cy vs ~40cy ds_swizzle)
template <int CTRL>
__device__ __forceinline__ float dppf(float x) {
    return __builtin_bit_cast(float, __builtin_amdgcn_update_dpp(
        0, __builtin_bit_cast(int, x), CTRL, 0xF, 0xF, true));
}
template <int CTRL>
__device__ __forceinline__ int dppi(int x) {
    return __builtin_amdgcn_update_dpp(0, x, CTRL, 0xF, 0xF, true);
}
// full 16-lane sum, every lane gets the total (butterfly over lane bits 0..3)
__device__ __forceinline__ float red16(float v) {
    v += dppf<0xB1>(v);    // quad_perm [1,0,3,2]  : xor 1
    v += dppf<0x4E>(v);    // quad_perm [2,3,0,1]  : xor 2
    v += dppf<0x141>(v);   // row_half_mirror      : pairs the two quads
    v += dppf<0x140>(v);   // row_mirror           : pairs the two halves
    return v;
}
__device__ __forceinline__ void wave_fence() {
    asm volatile("s_waitcnt lgkmcnt(0)" ::: "memory");
    __builtin_amdgcn_sched_barrier(0);  // rule #18
}

// P[8] per-lane projection partials -> xm for this lane's k
__device__ __forceinline__ float reduce_scatter(v2f P[8], int lane) {
    v2f Q[4];
#pragma unroll
    for (int r = 0; r < 4; ++r)
        Q[r] = swap32_sum(P[r], P[r+4]);   // lanes<32: k=2r,2r+1 ; lanes>=32: +8
    v2f S0 = swap16_sum(Q[0], Q[2]);       // b4=0: koff 0,1 ; b4=1: koff 4,5
    v2f S1 = swap16_sum(Q[1], Q[3]);       // b4=0: koff 2,3 ; b4=1: koff 6,7
    float a = red16(S0[0]), b = red16(S0[1]);
    float c = red16(S1[0]), d = red16(S1[1]);
    float lo = (lane & 1) ? b : a;
    float hi = (lane & 1) ? d : c;
    return (lane & 2) ? hi : lo;           // k = 8*b5 + 4*b4 + (lane&3)
}

// count-searchsorted + CDF interp + barycenter inverse-CDF -> coeff = xm - z
__device__ __forceinline__ float quantile_map(float xm, const float* ebRow,
                                              const float* cfRow, const float* bqk,
                                              const float e[8]) {
    int cnt = (e[0] <= xm) + (e[1] <= xm) + (e[2] <= xm) + (e[3] <= xm)
            + (e[4] <= xm) + (e[5] <= xm) + (e[6] <= xm) + (e[7] <= xm);
    cnt += dppi<0x124>(cnt);   // row_ror:4  (sums echunk pairs, preserves lane bits 0,1)
    cnt += dppi<0x128>(cnt);   // row_ror:8
    int i0 = min(max(cnt - 1, 0), NB - 1);
    float x0 = ebRow[i0], x1 = ebRow[i0+1];
    float f0 = cfRow[i0], f1 = cfRow[i0+1];
    float t  = fminf(fmaxf(__fdividef(xm - x0, x1 - x0), 0.f), 1.f);
    float u  = f0 + t * (f1 - f0);
    float posv = fminf(fmaxf(u, 0.f), 1.f) * (float)(GG - 1);
    int jj = min((int)posv, GG - 2);
    float ttf = posv - (float)jj;
    float b0 = bqk[jj], b1 = bqk[jj+1];
    return xm - (b0*(1.f - ttf) + b1*ttf);
}

__device__ __forceinline__ void out_row(v4f x, const float* cb, v2f (*wTo)[8],
                                        float* op) {
    v2f c2[8];
#pragma unroll
    for (int q = 0; q < 4; ++q) {
        v4f cv4 = *reinterpret_cast<const v4f*>(&cb[4*q]);   // broadcast read
        v2f a; a[0] = cv4[0]; a[1] = cv4[1]; c2[2*q]   = a;
        v2f b; b[0] = cv4[2]; b[1] = cv4[3]; c2[2*q+1] = b;
    }
    float od[4];
#pragma unroll
    for (int j = 0; j < 4; ++j) {
        v2f a = {0.f, 0.f};
#pragma unroll
        for (int q = 0; q < 8; ++q) pk_fma(a, c2[q], wTo[j][q]);
        od[j] = x[j] - (a[0] + a[1]);
    }
    v4f o4; o4[0] = od[0]; o4[1] = od[1]; o4[2] = od[2]; o4[3] = od[3];
    *reinterpret_cast<v4f*>(op) = o4;
}

__global__ __launch_bounds__(256, 4)   // proven-safe budget: no scratch at this bound
void inb_kernel(const float* __restrict__ X, const int* __restrict__ y,
                const float* __restrict__ wT, const float* __restrict__ be,
                const float* __restrict__ cv, const float* __restrict__ bq,
                float* __restrict__ out)
{
    // LDS: 16896 + 16896 + 6400 + 512 = 40704 B; 4 blocks/CU (= grid cap anyway)
    __shared__ alignas(16) float sEB[EB_N];
    __shared__ alignas(16) float sCDF[EB_N];
    __shared__ alignas(16) float sBARY[BARY_N];
    __shared__ alignas(16) float sCOEFF[WAVES][32];

    const int tid = threadIdx.x;
    for (int i = tid; i < EB_N; i += 256) { sEB[i] = be[i]; sCDF[i] = cv[i]; }
    for (int i = tid; i < BARY_N; i += 256) sBARY[i] = bq[i];
    __syncthreads();

    const int lane = tid & 63;
    const int wid  = tid >> 6;
    // k in lane bits 0,1,4,5; edge-chunk redundancy in bits 2,3
    const int k  = ((lane & 48) >> 2) | (lane & 3);
    const int ec = (lane >> 2) & 3;

    // wT rows 4l..4l+3, all 16 k — feeds projection partials AND output GEMM
    v2f wTo[4][8];
#pragma unroll
    for (int j = 0; j < 4; ++j) {
        const v4f* wrow = reinterpret_cast<const v4f*>(&wT[(4*lane + j)*KP]);
#pragma unroll
        for (int q = 0; q < 4; ++q) {
            v4f v = wrow[q];
            v2f a; a[0] = v[0]; a[1] = v[1]; wTo[j][2*q]   = a;
            v2f b; b[0] = v[2]; b[1] = v[3]; wTo[j][2*q+1] = b;
        }
    }

    float* cobuf = sCOEFF[wid];
    const int gwave = blockIdx.x * WAVES + wid;
    const int xoff  = 4*lane;

    // current pair (rows gwave+2it*NWAVE and +NWAVE); prefetch distance = 1 pair
    v4f xA = *reinterpret_cast<const v4f*>(&X[(size_t)gwave*DIM + xoff]);
    v4f xB = *reinterpret_cast<const v4f*>(&X[(size_t)(gwave + NWAVE)*DIM + xoff]);
    int dA = y[gwave], dB = y[gwave + NWAVE];

    for (int it = 0; it < PAIRS; ++it) {
        const int rA = gwave + (2*it)*NWAVE;
        const int rB = rA + NWAVE;

        // ---- edge reads (scalar: stride-33 rows are only 4B-aligned) ----
        const float* ebA = &sEB[(dA*KP + k)*(NB+1)];
        const float* ebB = &sEB[(dB*KP + k)*(NB+1)];
        float eA[8], eB[8];
#pragma unroll
        for (int t = 0; t < 8; ++t) { eA[t] = ebA[8*ec + t]; eB[t] = ebB[8*ec + t]; }

        // ---- prefetch next pair (clamped; unused on last iter) ----
        int nA = rA + 2*NWAVE; if (nA >= N_ROWS) nA = rA;
        int nB = nA + NWAVE;   if (nB >= N_ROWS) nB = rA;
        int dA_n = y[nA], dB_n = y[nB];
        v4f xA_n = *reinterpret_cast<const v4f*>(&X[(size_t)nA*DIM + xoff]);
        v4f xB_n = *reinterpret_cast<const v4f*>(&X[(size_t)nB*DIM + xoff]);

        // ---- projections (wTo element loaded once, feeds both rows) ----
        v2f PA[8], PB[8];
#pragma unroll
        for (int q = 0; q < 8; ++q) { PA[q] = (v2f){0.f,0.f}; PB[q] = (v2f){0.f,0.f}; }
#pragma unroll
        for (int j = 0; j < 4; ++j) {
            v2f aj; aj[0] = xA[j]; aj[1] = xA[j];
            v2f bj; bj[0] = xB[j]; bj[1] = xB[j];
#pragma unroll
            for (int q = 0; q < 8; ++q) {
                pk_fma(PA[q], aj, wTo[j][q]);
                pk_fma(PB[q], bj, wTo[j][q]);
            }
        }

        // ---- two independent reduce-scatter chains (VALU DPP) ----
        float xmA = reduce_scatter(PA, lane);
        float xmB = reduce_scatter(PB, lane);

        // ---- two independent scalar phases (4x redundant, divergence-free) ----
        float cA = quantile_map(xmA, ebA, &sCDF[(dA*KP + k)*(NB+1)], &sBARY[k*GG], eA);
        float cB = quantile_map(xmB, ebB, &sCDF[(dB*KP + k)*(NB+1)], &sBARY[k*GG], eB);

        if (ec < 2) cobuf[ec*16 + k] = (ec == 0) ? cA : cB;   // 32 lanes, 32 banks
        wave_fence();

        // ---- outputs: out[d] = x[d] - sum_k coeff[k]*wT[d][k] ----
        out_row(xA, cobuf,      wTo, &out[(size_t)rA*DIM + xoff]);
        out_row(xB, cobuf + 16, wTo, &out[(size_t)rB*DIM + xoff]);

        xA = xA_n; xB = xB_n; dA = dA_n; dB = dB_n;
    }
}

extern "C" void kernel_launch(void* const* d_in, const int* in_sizes, int n_in,
                              void* d_out, int out_size, void* d_ws, size_t ws_size,
                              hipStream_t stream) {
    const float* X  = (const float*)d_in[0];
    const int*   y  = (const int*)  d_in[1];
    const float* wT = (const float*)d_in[2];
    const float* be = (const float*)d_in[3];
    const float* cv = (const float*)d_in[4];
    const float* bq = (const float*)d_in[5];
    float* out = (float*)d_out;
    hipLaunchKernelGGL(inb_kernel, dim3(GRID), dim3(256), 0, stream,
                       X, y, wT, be, cv, bq, out);
}

// Round 11
// 69.227 us; speedup vs baseline: 6.2999x; 1.0271x over previous
//
#include <hip/hip_runtime.h>

typedef float v2f __attribute__((ext_vector_type(2)));
typedef float v4f __attribute__((ext_vector_type(4)));

#define N_ROWS 131072
#define DIM    256
#define KP     16
#define NDOM   8
#define NB     32      // bins
#define GG     100     // barycenter grid

#define EB_N   (NDOM*KP*(NB+1))   // 4224 floats
#define BARY_N (KP*GG)            // 1600

#define GRID   1024
#define WAVES  4
#define NWAVE  (GRID*WAVES)       // 4096 waves
#define PAIRS  16                 // 32 rows/wave, 2 rows per iteration, exact

// gfx950 half-swap ops (VALU): after swap, a+b = per-half partial sums
__device__ __forceinline__ void pl32swap(float &a, float &b) {
    asm("v_permlane32_swap_b32 %0, %1" : "+v"(a), "+v"(b));
}
__device__ __forceinline__ void pl16swap(float &a, float &b) {
    asm("v_permlane16_swap_b32 %0, %1" : "+v"(a), "+v"(b));
}
__device__ __forceinline__ v2f swap32_sum(v2f lo, v2f hi) {
    float a0 = lo[0], b0 = hi[0], a1 = lo[1], b1 = hi[1];
    pl32swap(a0, b0); pl32swap(a1, b1);
    v2f r; r[0] = a0 + b0; r[1] = a1 + b1; return r;
}
__device__ __forceinline__ v2f swap16_sum(v2f lo, v2f hi) {
    float a0 = lo[0], b0 = hi[0], a1 = lo[1], b1 = hi[1];
    pl16swap(a0, b0); pl16swap(a1, b1);
    v2f r; r[0] = a0 + b0; r[1] = a1 + b1; return r;
}
// DPP cross-lane (VALU pipe, ~4cy vs ~40cy ds_swizzle)
template <int CTRL>
__device__ __forceinline__ float dppf(float x) {
    return __builtin_bit_cast(float, __builtin_amdgcn_update_dpp(
        0, __builtin_bit_cast(int, x), CTRL, 0xF, 0xF, true));
}
template <int CTRL>
__device__ __forceinline__ int dppi(int x) {
    return __builtin_amdgcn_update_dpp(0, x, CTRL, 0xF, 0xF, true);
}
// full 16-lane sum, every lane gets the total (butterfly over lane bits 0..3)
__device__ __forceinline__ float red16(float v) {
    v += dppf<0xB1>(v);    // quad_perm [1,0,3,2]  : xor 1
    v += dppf<0x4E>(v);    // quad_perm [2,3,0,1]  : xor 2
    v += dppf<0x141>(v);   // row_half_mirror      : pairs the two quads
    v += dppf<0x140>(v);   // row_mirror           : pairs the two halves
    return v;
}
__device__ __forceinline__ void wave_fence() {
    asm volatile("s_waitcnt lgkmcnt(0)" ::: "memory");
    __builtin_amdgcn_sched_barrier(0);  // rule #18
}

// P[8] per-lane projection partials -> xm for this lane's k
__device__ __forceinline__ float reduce_scatter(v2f P[8], int lane) {
    v2f Q[4];
#pragma unroll
    for (int r = 0; r < 4; ++r)
        Q[r] = swap32_sum(P[r], P[r+4]);   // lanes<32: k=2r,2r+1 ; lanes>=32: +8
    v2f S0 = swap16_sum(Q[0], Q[2]);       // b4=0: koff 0,1 ; b4=1: koff 4,5
    v2f S1 = swap16_sum(Q[1], Q[3]);       // b4=0: koff 2,3 ; b4=1: koff 6,7
    float a = red16(S0[0]), b = red16(S0[1]);
    float c = red16(S1[0]), d = red16(S1[1]);
    float lo = (lane & 1) ? b : a;
    float hi = (lane & 1) ? d : c;
    return (lane & 2) ? hi : lo;           // k = 8*b5 + 4*b4 + (lane&3)
}

// count-searchsorted + CDF interp + barycenter inverse-CDF -> coeff = xm - z
__device__ __forceinline__ float quantile_map(float xm, const float* ebRow,
                                              const float* cfRow, const float* bqk,
                                              const float e[8]) {
    int cnt = (e[0] <= xm) + (e[1] <= xm) + (e[2] <= xm) + (e[3] <= xm)
            + (e[4] <= xm) + (e[5] <= xm) + (e[6] <= xm) + (e[7] <= xm);
    cnt += dppi<0x124>(cnt);   // row_ror:4  (sums echunk groups, preserves lane bits 0,1)
    cnt += dppi<0x128>(cnt);   // row_ror:8
    int i0 = min(max(cnt - 1, 0), NB - 1);
    float x0 = ebRow[i0], x1 = ebRow[i0+1];
    float f0 = cfRow[i0], f1 = cfRow[i0+1];
    float t  = fminf(fmaxf(__fdividef(xm - x0, x1 - x0), 0.f), 1.f);
    float u  = f0 + t * (f1 - f0);
    float posv = fminf(fmaxf(u, 0.f), 1.f) * (float)(GG - 1);
    int jj = min((int)posv, GG - 2);
    float ttf = posv - (float)jj;
    float b0 = bqk[jj], b1 = bqk[jj+1];
    return xm - (b0*(1.f - ttf) + b1*ttf);
}

// plain v2f arithmetic: compiler emits v_pk_fma_f32 and can schedule/fold freely
__device__ __forceinline__ void proj_row(v4f x, const v2f wTo[4][8], v2f P[8]) {
#pragma unroll
    for (int q = 0; q < 8; ++q) P[q] = (v2f){0.f, 0.f};
#pragma unroll
    for (int j = 0; j < 4; ++j) {
        v2f xj = {x[j], x[j]};
#pragma unroll
        for (int q = 0; q < 8; ++q) P[q] += xj * wTo[j][q];
    }
}

__device__ __forceinline__ void out_row(v4f x, const float* cb, const v2f wTo[4][8],
                                        float* op) {
    v2f c2[8];
#pragma unroll
    for (int q = 0; q < 4; ++q) {
        v4f cv4 = *reinterpret_cast<const v4f*>(&cb[4*q]);   // broadcast read
        c2[2*q]   = (v2f){cv4[0], cv4[1]};
        c2[2*q+1] = (v2f){cv4[2], cv4[3]};
    }
    v4f o4;
#pragma unroll
    for (int j = 0; j < 4; ++j) {
        v2f a = c2[0] * wTo[j][0];
#pragma unroll
        for (int q = 1; q < 8; ++q) a += c2[q] * wTo[j][q];
        o4[j] = x[j] - (a[0] + a[1]);
    }
    *reinterpret_cast<v4f*>(op) = o4;
}

__global__ __launch_bounds__(256, 4)   // proven-safe budget (R4/R9): no scratch
void inb_kernel(const float* __restrict__ X, const int* __restrict__ y,
                const float* __restrict__ wT, const float* __restrict__ be,
                const float* __restrict__ cv, const float* __restrict__ bq,
                float* __restrict__ out)
{
    // LDS: 16896 + 16896 + 6400 + 512 = 40704 B; 4 blocks/CU (= grid cap anyway)
    __shared__ alignas(16) float sEB[EB_N];
    __shared__ alignas(16) float sCDF[EB_N];
    __shared__ alignas(16) float sBARY[BARY_N];
    __shared__ alignas(16) float sCOEFF[WAVES][32];

    const int tid = threadIdx.x;
    for (int i = tid; i < EB_N; i += 256) { sEB[i] = be[i]; sCDF[i] = cv[i]; }
    for (int i = tid; i < BARY_N; i += 256) sBARY[i] = bq[i];
    __syncthreads();

    const int lane = tid & 63;
    const int wid  = tid >> 6;
    const int k  = ((lane & 48) >> 2) | (lane & 3);   // k in lane bits 0,1,4,5
    const int ec = (lane >> 2) & 3;                   // edge-chunk in bits 2,3

    // wT rows 4l..4l+3, all 16 k — feeds projection partials AND output GEMM
    v2f wTo[4][8];
#pragma unroll
    for (int j = 0; j < 4; ++j) {
        const v4f* wrow = reinterpret_cast<const v4f*>(&wT[(4*lane + j)*KP]);
#pragma unroll
        for (int q = 0; q < 4; ++q) {
            v4f v = wrow[q];
            wTo[j][2*q]   = (v2f){v[0], v[1]};
            wTo[j][2*q+1] = (v2f){v[2], v[3]};
        }
    }

    float* cobuf = sCOEFF[wid];
    const int gwave = blockIdx.x * WAVES + wid;
    const int xoff  = 4*lane;

    v4f xA = *reinterpret_cast<const v4f*>(&X[(size_t)gwave*DIM + xoff]);
    v4f xB = *reinterpret_cast<const v4f*>(&X[(size_t)(gwave + NWAVE)*DIM + xoff]);
    int dA = y[gwave], dB = y[gwave + NWAVE];

    for (int it = 0; it < PAIRS; ++it) {
        const int rA = gwave + (2*it)*NWAVE;
        const int rB = rA + NWAVE;

        // edge reads first (depend only on prefetched dom)
        const float* ebA = &sEB[(dA*KP + k)*(NB+1)];
        const float* ebB = &sEB[(dB*KP + k)*(NB+1)];
        float eA[8], eB[8];
#pragma unroll
        for (int t = 0; t < 8; ++t) { eA[t] = ebA[8*ec + t]; eB[t] = ebB[8*ec + t]; }

        // prefetch next pair (clamped; unused on last iter)
        int nA = rA + 2*NWAVE; if (nA >= N_ROWS) nA = rA;
        int nB = nA + NWAVE;   if (nB >= N_ROWS) nB = rA;
        int dA_n = y[nA], dB_n = y[nB];
        v4f xA_n = *reinterpret_cast<const v4f*>(&X[(size_t)nA*DIM + xoff]);
        v4f xB_n = *reinterpret_cast<const v4f*>(&X[(size_t)nB*DIM + xoff]);

        v2f PA[8], PB[8];
        proj_row(xA, wTo, PA);
        proj_row(xB, wTo, PB);

        float xmA = reduce_scatter(PA, lane);
        float xmB = reduce_scatter(PB, lane);

        float cA = quantile_map(xmA, ebA, &sCDF[(dA*KP + k)*(NB+1)], &sBARY[k*GG], eA);
        float cB = quantile_map(xmB, ebB, &sCDF[(dB*KP + k)*(NB+1)], &sBARY[k*GG], eB);

        if (ec < 2) cobuf[ec*16 + k] = (ec == 0) ? cA : cB;   // 32 lanes, 32 banks
        wave_fence();

        out_row(xA, cobuf,      wTo, &out[(size_t)rA*DIM + xoff]);
        out_row(xB, cobuf + 16, wTo, &out[(size_t)rB*DIM + xoff]);

        xA = xA_n; xB = xB_n; dA = dA_n; dB = dB_n;
    }
}

extern "C" void kernel_launch(void* const* d_in, const int* in_sizes, int n_in,
                              void* d_out, int out_size, void* d_ws, size_t ws_size,
                              hipStream_t stream) {
    const float* X  = (const float*)d_in[0];
    const int*   y  = (const int*)  d_in[1];
    const float* wT = (const float*)d_in[2];
    const float* be = (const float*)d_in[3];
    const float* cv = (const float*)d_in[4];
    const float* bq = (const float*)d_in[5];
    float* out = (float*)d_out;
    hipLaunchKernelGGL(inb_kernel, dim3(GRID), dim3(256), 0, stream,
                       X, y, wT, be, cv, bq, out);
}